// Round 6
// baseline (20831.534 us; speedup 1.0000x reference)
//
#include <hip/hip_runtime.h>
#include <hip/hip_bf16.h>

// Problem constants: N=8192, Din=1024, H=1024, 4H=4096.
#define NSTEP 8192
#define DIN   1024
#define HDIM  1024
#define G4    4096

typedef float f32x4 __attribute__((ext_vector_type(4)));

// ---------------------------------------------------------------------------
// Phase A: x_gates[n][m] = dot(xs[n,:], W_ih[m,:]) + b_ih[m] + b_hh[m]
// ---------------------------------------------------------------------------
__global__ __launch_bounds__(256) void gemm_xgates(
    const float* __restrict__ xs,    // [8192,1024]
    const float* __restrict__ Wih,   // [4096,1024]
    const float* __restrict__ bih,   // [4096]
    const float* __restrict__ bhh,   // [4096]
    float* __restrict__ xg)          // [8192,4096]
{
    __shared__ float a_s[32][68];
    __shared__ float b_s[32][68];

    const int bm = blockIdx.x;
    const int bn = blockIdx.y;
    const int tid = threadIdx.x;
    const int tx = tid & 15;
    const int ty = tid >> 4;

    float acc[4][4] = {};

    for (int k0 = 0; k0 < DIN; k0 += 32) {
        #pragma unroll
        for (int s = tid; s < 512; s += 256) {
            const int r  = s >> 3;
            const int kk = (s & 7) << 2;
            const float4 av = *(const float4*)&xs[(size_t)(bn * 64 + r) * DIN + k0 + kk];
            a_s[kk + 0][r] = av.x; a_s[kk + 1][r] = av.y;
            a_s[kk + 2][r] = av.z; a_s[kk + 3][r] = av.w;
            const float4 bv = *(const float4*)&Wih[(size_t)(bm * 64 + r) * DIN + k0 + kk];
            b_s[kk + 0][r] = bv.x; b_s[kk + 1][r] = bv.y;
            b_s[kk + 2][r] = bv.z; b_s[kk + 3][r] = bv.w;
        }
        __syncthreads();

        #pragma unroll
        for (int k = 0; k < 32; ++k) {
            const float4 a = *(const float4*)&a_s[k][ty << 2];
            const float4 b = *(const float4*)&b_s[k][tx << 2];
            acc[0][0] = fmaf(a.x, b.x, acc[0][0]); acc[0][1] = fmaf(a.x, b.y, acc[0][1]);
            acc[0][2] = fmaf(a.x, b.z, acc[0][2]); acc[0][3] = fmaf(a.x, b.w, acc[0][3]);
            acc[1][0] = fmaf(a.y, b.x, acc[1][0]); acc[1][1] = fmaf(a.y, b.y, acc[1][1]);
            acc[1][2] = fmaf(a.y, b.z, acc[1][2]); acc[1][3] = fmaf(a.y, b.w, acc[1][3]);
            acc[2][0] = fmaf(a.z, b.x, acc[2][0]); acc[2][1] = fmaf(a.z, b.y, acc[2][1]);
            acc[2][2] = fmaf(a.z, b.z, acc[2][2]); acc[2][3] = fmaf(a.z, b.w, acc[2][3]);
            acc[3][0] = fmaf(a.w, b.x, acc[3][0]); acc[3][1] = fmaf(a.w, b.y, acc[3][1]);
            acc[3][2] = fmaf(a.w, b.z, acc[3][2]); acc[3][3] = fmaf(a.w, b.w, acc[3][3]);
        }
        __syncthreads();
    }

    const int m0 = bm * 64 + (tx << 2);
    const float4 bias = make_float4(bih[m0 + 0] + bhh[m0 + 0],
                                    bih[m0 + 1] + bhh[m0 + 1],
                                    bih[m0 + 2] + bhh[m0 + 2],
                                    bih[m0 + 3] + bhh[m0 + 3]);
    #pragma unroll
    for (int u = 0; u < 4; ++u) {
        const int n = bn * 64 + (ty << 2) + u;
        float4 v = make_float4(acc[u][0] + bias.x, acc[u][1] + bias.y,
                               acc[u][2] + bias.z, acc[u][3] + bias.w);
        *(float4*)&xg[(size_t)n * G4 + m0] = v;
    }
}

// ---------------------------------------------------------------------------
// Phase B: persistent recurrence. 128 WGs x 512 threads (cooperative).
// WG w owns h[w*8 .. w*8+8) -> 32 gate rows. Each WAVE owns 4 rows with a
// full-wave k-split: lane covers f32x4 chunks c = lane + 64*i (i=0..3), so
// the h read is 4 consecutive-address ds_read_b128 (canonical conflict-free)
// and W is 16 f32x4 = 64 floats/thread pinned in AGPRs via explicit
// v_accvgpr_write/read inline asm — asm-defined values cannot be
// rematerialized (the R2-R4 "+v" pin failed; R5's W-in-LDS was LDS-pipe
// bound at 128KB/step/CU + 4-way bank conflicts).
// Sync: R5's proven data-as-flag slots {tag,h} 8B agent-relaxed atomics,
// double-buffered by parity, per-thread self-poll. Zero fences, zero RMW.
// xg prefetch depth 2 (t+2) so the HBM stream stays off the critical path.
// ---------------------------------------------------------------------------
#define REC_G 128
#define REC_T 512
#define HPW   8
#define ROWS  32

__global__ __launch_bounds__(REC_T) void lstm_rec(
    const float* __restrict__ xg,    // [NSTEP, 4096]
    const float* __restrict__ Whh,   // [4096, 1024]
    const float* __restrict__ h0,    // [1024]
    const float* __restrict__ c0,    // [1024]
    float* __restrict__ ys,          // [NSTEP, 1024]
    unsigned long long* slots)       // [2][1024] ws, memset 0 pre-launch
{
    __shared__ float h_lds[HDIM];
    __shared__ float gacc[ROWS];

    const int tid  = threadIdx.x;
    const int lane = tid & 63;
    const int wv   = tid >> 6;            // 0..7 ; wave owns rows wv*4..wv*4+3
    const int wg   = blockIdx.x;          // 0..127
    const int j0   = wg * HPW;

    // ---- stage W strip and pin in AGPRs ----
    // wtmp[r*4+i] = Whh[grow(wv*4+r)][ (lane+64i)*4 .. +3 ]
    f32x4 wtmp[16];
    #pragma unroll
    for (int r = 0; r < 4; ++r) {
        const int rowloc = (wv << 2) + r;                  // 0..31 (= q*8+j)
        const int grow   = (rowloc >> 3) * HDIM + j0 + (rowloc & 7);
        const float* wb  = Whh + (size_t)grow * HDIM;
        #pragma unroll
        for (int i = 0; i < 4; ++i)
            wtmp[r * 4 + i] = *(const f32x4*)(wb + ((lane + (i << 6)) << 2));
    }
    float wa[64];
    #pragma unroll
    for (int e = 0; e < 64; ++e) {
        const float v = ((const float*)wtmp)[e];
        asm("v_accvgpr_write_b32 %0, %1" : "=a"(wa[e]) : "v"(v));
    }

    // ---- init: h0 -> LDS; c + xg rows 0,1 -> gating-lane registers ----
    ((float2*)h_lds)[tid] = ((const float2*)h0)[tid];
    float c_reg = 0.f;
    float xc0 = 0.f, xc1 = 0.f, xc2 = 0.f, xc3 = 0.f;   // xg row t   (cur)
    float xn0 = 0.f, xn1 = 0.f, xn2 = 0.f, xn3 = 0.f;   // xg row t+1 (next)
    if (tid < HPW) {
        c_reg = c0[j0 + tid];
        xc0 = xg[0 * HDIM + j0 + tid];
        xc1 = xg[1 * HDIM + j0 + tid];
        xc2 = xg[2 * HDIM + j0 + tid];
        xc3 = xg[3 * HDIM + j0 + tid];
        xn0 = xg[(size_t)G4 + 0 * HDIM + j0 + tid];
        xn1 = xg[(size_t)G4 + 1 * HDIM + j0 + tid];
        xn2 = xg[(size_t)G4 + 2 * HDIM + j0 + tid];
        xn3 = xg[(size_t)G4 + 3 * HDIM + j0 + tid];
    }
    __syncthreads();

    const f32x4* hv4 = (const f32x4*)h_lds;

    for (int t = 0; t < NSTEP; ++t) {
        // ---- dot: W from AGPRs, h from LDS (4 ds_read_b128, consecutive) ----
        float a0 = 0.f, a1 = 0.f, a2 = 0.f, a3 = 0.f;
        #pragma unroll
        for (int i = 0; i < 4; ++i) {
            const f32x4 hv = hv4[lane + (i << 6)];
            #pragma unroll
            for (int r = 0; r < 4; ++r) {
                float w0, w1, w2, w3;
                asm("v_accvgpr_read_b32 %0, %1" : "=v"(w0) : "a"(wa[r * 16 + i * 4 + 0]));
                asm("v_accvgpr_read_b32 %0, %1" : "=v"(w1) : "a"(wa[r * 16 + i * 4 + 1]));
                asm("v_accvgpr_read_b32 %0, %1" : "=v"(w2) : "a"(wa[r * 16 + i * 4 + 2]));
                asm("v_accvgpr_read_b32 %0, %1" : "=v"(w3) : "a"(wa[r * 16 + i * 4 + 3]));
                float s = (r == 0) ? a0 : (r == 1) ? a1 : (r == 2) ? a2 : a3;
                s = fmaf(w0, hv.x, s);
                s = fmaf(w1, hv.y, s);
                s = fmaf(w2, hv.z, s);
                s = fmaf(w3, hv.w, s);
                if (r == 0) a0 = s; else if (r == 1) a1 = s;
                else if (r == 2) a2 = s; else a3 = s;
            }
        }
        // full-wave butterfly reduce (4 rows in parallel)
        #pragma unroll
        for (int m = 1; m < 64; m <<= 1) {
            a0 += __shfl_xor(a0, m);
            a1 += __shfl_xor(a1, m);
            a2 += __shfl_xor(a2, m);
            a3 += __shfl_xor(a3, m);
        }
        if (lane == 0) {
            gacc[(wv << 2) + 0] = a0;
            gacc[(wv << 2) + 1] = a1;
            gacc[(wv << 2) + 2] = a2;
            gacc[(wv << 2) + 3] = a3;
        }
        __syncthreads();   // #1: gacc ready; h_lds reads of step t complete

        // ---- gating (lanes 0-7 of wave 0): state update + publish ----
        if (tid < HPW) {
            const float gi = gacc[ 0 + tid] + xc0;
            const float gf = gacc[ 8 + tid] + xc1;
            const float gg = gacc[16 + tid] + xc2;
            const float go = gacc[24 + tid] + xc3;
            const float i_ = 1.f / (1.f + __expf(-gi));
            const float f_ = 1.f / (1.f + __expf(-gf));
            const float g_ = 2.f / (1.f + __expf(-2.f * gg)) - 1.f;
            const float o_ = 1.f / (1.f + __expf(-go));
            c_reg = f_ * c_reg + i_ * g_;
            const float h_ = o_ * (2.f / (1.f + __expf(-2.f * c_reg)) - 1.f);

            if (t + 1 < NSTEP) {
                // publish: ONE self-contained 8B atomic (tag | h bits)
                const unsigned long long pk =
                    ((unsigned long long)(unsigned)(t + 1) << 32) |
                    (unsigned long long)__float_as_uint(h_);
                __hip_atomic_store(&slots[((t + 1) & 1) * HDIM + j0 + tid], pk,
                                   __ATOMIC_RELAXED, __HIP_MEMORY_SCOPE_AGENT);
            }
            // off critical path: output + rotate prefetch, fetch t+2
            ys[(size_t)t * HDIM + j0 + tid] = h_;
            xc0 = xn0; xc1 = xn1; xc2 = xn2; xc3 = xn3;
            if (t + 2 < NSTEP) {
                const size_t xb = (size_t)(t + 2) * G4 + j0 + tid;
                xn0 = xg[xb + 0 * HDIM];
                xn1 = xg[xb + 1 * HDIM];
                xn2 = xg[xb + 2 * HDIM];
                xn3 = xg[xb + 3 * HDIM];
            }
        }
        if (t + 1 == NSTEP) break;

        // ---- every thread polls its own 2 slots (fully parallel) ----
        {
            const unsigned long long* sp = slots + ((t + 1) & 1) * HDIM;
            const unsigned long long want =
                (unsigned long long)(unsigned)(t + 1) << 32;
            unsigned long long s0, s1;
            do {
                s0 = __hip_atomic_load(&sp[2 * tid], __ATOMIC_RELAXED,
                                       __HIP_MEMORY_SCOPE_AGENT);
            } while (s0 < want);
            do {
                s1 = __hip_atomic_load(&sp[2 * tid + 1], __ATOMIC_RELAXED,
                                       __HIP_MEMORY_SCOPE_AGENT);
            } while (s1 < want);
            h_lds[2 * tid]     = __uint_as_float((unsigned)s0);
            h_lds[2 * tid + 1] = __uint_as_float((unsigned)s1);
        }
        __syncthreads();   // #2: h_lds ready for next step
    }
}

// ---------------------------------------------------------------------------
extern "C" void kernel_launch(void* const* d_in, const int* in_sizes, int n_in,
                              void* d_out, int out_size, void* d_ws, size_t ws_size,
                              hipStream_t stream) {
    const float* xs  = (const float*)d_in[0];
    const float* Wih = (const float*)d_in[1];
    const float* Whh = (const float*)d_in[2];
    const float* bih = (const float*)d_in[3];
    const float* bhh = (const float*)d_in[4];
    const float* h0  = (const float*)d_in[5];
    const float* c0  = (const float*)d_in[6];
    float* ys = (float*)d_out;

    const size_t XG_BYTES = (size_t)NSTEP * G4 * sizeof(float);   // 134 MB
    float* xg = (float*)d_ws;
    unsigned long long* slots =
        (unsigned long long*)((char*)d_ws + XG_BYTES);            // 16 KB

    // kill stale tags from previous graph replay (deterministic per call)
    hipMemsetAsync(slots, 0, 2 * HDIM * sizeof(unsigned long long), stream);

    dim3 gridA(G4 / 64, NSTEP / 64);
    gemm_xgates<<<gridA, 256, 0, stream>>>(xs, Wih, bih, bhh, xg);

    void* args[] = {(void*)&xg, (void*)&Whh, (void*)&h0, (void*)&c0,
                    (void*)&ys, (void*)&slots};
    hipLaunchCooperativeKernel((void*)lstm_rec, dim3(REC_G), dim3(REC_T),
                               args, 0, stream);
}

// Round 7
// 15554.704 us; speedup vs baseline: 1.3392x; 1.3392x over previous
//
#include <hip/hip_runtime.h>
#include <hip/hip_bf16.h>

// Problem constants: N=8192, Din=1024, H=1024, 4H=4096.
#define NSTEP 8192
#define DIN   1024
#define HDIM  1024
#define G4    4096

typedef float f32x4 __attribute__((ext_vector_type(4)));

// ---------------------------------------------------------------------------
// Phase A: x_gates[n][m] = dot(xs[n,:], W_ih[m,:]) + b_ih[m] + b_hh[m]
// ---------------------------------------------------------------------------
__global__ __launch_bounds__(256) void gemm_xgates(
    const float* __restrict__ xs,    // [8192,1024]
    const float* __restrict__ Wih,   // [4096,1024]
    const float* __restrict__ bih,   // [4096]
    const float* __restrict__ bhh,   // [4096]
    float* __restrict__ xg)          // [8192,4096]
{
    __shared__ float a_s[32][68];
    __shared__ float b_s[32][68];

    const int bm = blockIdx.x;
    const int bn = blockIdx.y;
    const int tid = threadIdx.x;
    const int tx = tid & 15;
    const int ty = tid >> 4;

    float acc[4][4] = {};

    for (int k0 = 0; k0 < DIN; k0 += 32) {
        #pragma unroll
        for (int s = tid; s < 512; s += 256) {
            const int r  = s >> 3;
            const int kk = (s & 7) << 2;
            const float4 av = *(const float4*)&xs[(size_t)(bn * 64 + r) * DIN + k0 + kk];
            a_s[kk + 0][r] = av.x; a_s[kk + 1][r] = av.y;
            a_s[kk + 2][r] = av.z; a_s[kk + 3][r] = av.w;
            const float4 bv = *(const float4*)&Wih[(size_t)(bm * 64 + r) * DIN + k0 + kk];
            b_s[kk + 0][r] = bv.x; b_s[kk + 1][r] = bv.y;
            b_s[kk + 2][r] = bv.z; b_s[kk + 3][r] = bv.w;
        }
        __syncthreads();

        #pragma unroll
        for (int k = 0; k < 32; ++k) {
            const float4 a = *(const float4*)&a_s[k][ty << 2];
            const float4 b = *(const float4*)&b_s[k][tx << 2];
            acc[0][0] = fmaf(a.x, b.x, acc[0][0]); acc[0][1] = fmaf(a.x, b.y, acc[0][1]);
            acc[0][2] = fmaf(a.x, b.z, acc[0][2]); acc[0][3] = fmaf(a.x, b.w, acc[0][3]);
            acc[1][0] = fmaf(a.y, b.x, acc[1][0]); acc[1][1] = fmaf(a.y, b.y, acc[1][1]);
            acc[1][2] = fmaf(a.y, b.z, acc[1][2]); acc[1][3] = fmaf(a.y, b.w, acc[1][3]);
            acc[2][0] = fmaf(a.z, b.x, acc[2][0]); acc[2][1] = fmaf(a.z, b.y, acc[2][1]);
            acc[2][2] = fmaf(a.z, b.z, acc[2][2]); acc[2][3] = fmaf(a.z, b.w, acc[2][3]);
            acc[3][0] = fmaf(a.w, b.x, acc[3][0]); acc[3][1] = fmaf(a.w, b.y, acc[3][1]);
            acc[3][2] = fmaf(a.w, b.z, acc[3][2]); acc[3][3] = fmaf(a.w, b.w, acc[3][3]);
        }
        __syncthreads();
    }

    const int m0 = bm * 64 + (tx << 2);
    const float4 bias = make_float4(bih[m0 + 0] + bhh[m0 + 0],
                                    bih[m0 + 1] + bhh[m0 + 1],
                                    bih[m0 + 2] + bhh[m0 + 2],
                                    bih[m0 + 3] + bhh[m0 + 3]);
    #pragma unroll
    for (int u = 0; u < 4; ++u) {
        const int n = bn * 64 + (ty << 2) + u;
        float4 v = make_float4(acc[u][0] + bias.x, acc[u][1] + bias.y,
                               acc[u][2] + bias.z, acc[u][3] + bias.w);
        *(float4*)&xg[(size_t)n * G4 + m0] = v;
    }
}

// ---------------------------------------------------------------------------
// Phase B: persistent recurrence. 128 WGs x 512 threads (cooperative).
// WAVE-AUTONOMOUS ROWS: wave wv owns ALL FOUR gate rows of j = wg*8+wv,
// with a full-wave k-split (lane covers f32x4 chunks c = lane + 64*i,
// i=0..3 -> 4 consecutive-address ds_read_b128, conflict-free). After the
// 6-step butterfly EVERY lane holds all 4 gate sums -> gating is computed
// redundantly wave-wide (same wave-cycles as 1 lane), lane 0 publishes.
// This deletes barrier #1 and the gacc LDS round-trip of R1-R6.
// W: 16 f32x4/thread in VGPRs, R3-proven pin (waves_per_eu(2,2) + two
// 8-operand "+v" asm pins; R6's AGPR reads put 64 VALU ops on the critical
// path - reverted).
// h_lds double-buffered by parity -> the fill of step t+1 can't race step
// t's readers -> exactly ONE __syncthreads per step.
// Sync: R5's data-as-flag slots {tag,h} (8B agent-relaxed atomics, parity
// double-buffer, monotonic tags; overwrite-safety argument in R5 notes).
// ---------------------------------------------------------------------------
#define REC_G 128
#define REC_T 512
#define HPW   8

__global__ __attribute__((amdgpu_waves_per_eu(2, 2)))
__launch_bounds__(REC_T) void lstm_rec(
    const float* __restrict__ xg,    // [NSTEP, 4096]
    const float* __restrict__ Whh,   // [4096, 1024]
    const float* __restrict__ h0,    // [1024]
    const float* __restrict__ c0,    // [1024]
    float* __restrict__ ys,          // [NSTEP, 1024]
    unsigned long long* slots)       // [2][1024] ws, memset 0 pre-launch
{
    __shared__ float h_lds[2][HDIM];

    const int tid   = threadIdx.x;
    const int lane  = tid & 63;
    const int wv    = tid >> 6;           // 0..7
    const int wg    = blockIdx.x;         // 0..127
    const int jglob = wg * HPW + wv;      // this wave's hidden index

    // ---- stage W: w[r*4+i] = Whh[r*HDIM + jglob][4*(lane+64i) .. +3] ----
    f32x4 w[16];
    #pragma unroll
    for (int r = 0; r < 4; ++r) {
        const float* wb = Whh + (size_t)(r * HDIM + jglob) * HDIM;
        #pragma unroll
        for (int i = 0; i < 4; ++i)
            w[r * 4 + i] = *(const f32x4*)(wb + ((lane + (i << 6)) << 2));
    }
    asm volatile("" : "+v"(w[0]), "+v"(w[1]), "+v"(w[2]), "+v"(w[3]),
                      "+v"(w[4]), "+v"(w[5]), "+v"(w[6]), "+v"(w[7]));
    asm volatile("" : "+v"(w[8]), "+v"(w[9]), "+v"(w[10]), "+v"(w[11]),
                      "+v"(w[12]), "+v"(w[13]), "+v"(w[14]), "+v"(w[15]));

    // ---- init: h0 -> buffer 0; c + xg rows 0,1 redundant on all lanes ----
    ((float2*)h_lds[0])[tid] = ((const float2*)h0)[tid];
    float c_reg = c0[jglob];                       // wave-broadcast load
    float xc0 = xg[0 * HDIM + jglob];
    float xc1 = xg[1 * HDIM + jglob];
    float xc2 = xg[2 * HDIM + jglob];
    float xc3 = xg[3 * HDIM + jglob];
    float xn0 = xg[(size_t)G4 + 0 * HDIM + jglob];
    float xn1 = xg[(size_t)G4 + 1 * HDIM + jglob];
    float xn2 = xg[(size_t)G4 + 2 * HDIM + jglob];
    float xn3 = xg[(size_t)G4 + 3 * HDIM + jglob];
    __syncthreads();

    for (int t = 0; t < NSTEP; ++t) {
        const f32x4* hb = (const f32x4*)h_lds[t & 1];

        // ---- dot: W in VGPRs, h from LDS (4 ds_read_b128, consecutive) ----
        float a0 = 0.f, a1 = 0.f, a2 = 0.f, a3 = 0.f;
        #pragma unroll
        for (int i = 0; i < 4; ++i) {
            const f32x4 hv = hb[lane + (i << 6)];
            a0 = fmaf(w[0  + i].x, hv.x, a0); a0 = fmaf(w[0  + i].y, hv.y, a0);
            a0 = fmaf(w[0  + i].z, hv.z, a0); a0 = fmaf(w[0  + i].w, hv.w, a0);
            a1 = fmaf(w[4  + i].x, hv.x, a1); a1 = fmaf(w[4  + i].y, hv.y, a1);
            a1 = fmaf(w[4  + i].z, hv.z, a1); a1 = fmaf(w[4  + i].w, hv.w, a1);
            a2 = fmaf(w[8  + i].x, hv.x, a2); a2 = fmaf(w[8  + i].y, hv.y, a2);
            a2 = fmaf(w[8  + i].z, hv.z, a2); a2 = fmaf(w[8  + i].w, hv.w, a2);
            a3 = fmaf(w[12 + i].x, hv.x, a3); a3 = fmaf(w[12 + i].y, hv.y, a3);
            a3 = fmaf(w[12 + i].z, hv.z, a3); a3 = fmaf(w[12 + i].w, hv.w, a3);
        }
        #pragma unroll
        for (int m = 1; m < 64; m <<= 1) {
            a0 += __shfl_xor(a0, m);
            a1 += __shfl_xor(a1, m);
            a2 += __shfl_xor(a2, m);
            a3 += __shfl_xor(a3, m);
        }

        // ---- gating: redundant on all 64 lanes (same cycles as 1 lane) ----
        const float gi = a0 + xc0;
        const float gf = a1 + xc1;
        const float gg = a2 + xc2;
        const float go = a3 + xc3;
        const float i_ = 1.f / (1.f + __expf(-gi));
        const float f_ = 1.f / (1.f + __expf(-gf));
        const float g_ = 2.f / (1.f + __expf(-2.f * gg)) - 1.f;
        const float o_ = 1.f / (1.f + __expf(-go));
        c_reg = f_ * c_reg + i_ * g_;
        const float h_ = o_ * (2.f / (1.f + __expf(-2.f * c_reg)) - 1.f);

        // ---- publish ASAP (lane 0), then off-critical-path work ----
        if (lane == 0) {
            if (t + 1 < NSTEP) {
                const unsigned long long pk =
                    ((unsigned long long)(unsigned)(t + 1) << 32) |
                    (unsigned long long)__float_as_uint(h_);
                __hip_atomic_store(&slots[((t + 1) & 1) * HDIM + jglob], pk,
                                   __ATOMIC_RELAXED, __HIP_MEMORY_SCOPE_AGENT);
            }
            ys[(size_t)t * HDIM + jglob] = h_;
        }
        xc0 = xn0; xc1 = xn1; xc2 = xn2; xc3 = xn3;
        if (t + 2 < NSTEP) {
            const size_t xb = (size_t)(t + 2) * G4 + jglob;
            xn0 = xg[xb + 0 * HDIM];
            xn1 = xg[xb + 1 * HDIM];
            xn2 = xg[xb + 2 * HDIM];
            xn3 = xg[xb + 3 * HDIM];
        }
        if (t + 1 == NSTEP) break;

        // ---- poll own 2 slots (both loads in flight per iteration) ----
        {
            const unsigned long long* sp = slots + ((t + 1) & 1) * HDIM;
            const unsigned long long want =
                (unsigned long long)(unsigned)(t + 1) << 32;
            unsigned long long s0, s1;
            do {
                s0 = __hip_atomic_load(&sp[2 * tid], __ATOMIC_RELAXED,
                                       __HIP_MEMORY_SCOPE_AGENT);
                s1 = __hip_atomic_load(&sp[2 * tid + 1], __ATOMIC_RELAXED,
                                       __HIP_MEMORY_SCOPE_AGENT);
            } while (s0 < want || s1 < want);
            float2 hv;
            hv.x = __uint_as_float((unsigned)s0);
            hv.y = __uint_as_float((unsigned)s1);
            ((float2*)h_lds[(t + 1) & 1])[tid] = hv;
        }
        __syncthreads();   // the ONLY barrier per step
    }
}

// ---------------------------------------------------------------------------
extern "C" void kernel_launch(void* const* d_in, const int* in_sizes, int n_in,
                              void* d_out, int out_size, void* d_ws, size_t ws_size,
                              hipStream_t stream) {
    const float* xs  = (const float*)d_in[0];
    const float* Wih = (const float*)d_in[1];
    const float* Whh = (const float*)d_in[2];
    const float* bih = (const float*)d_in[3];
    const float* bhh = (const float*)d_in[4];
    const float* h0  = (const float*)d_in[5];
    const float* c0  = (const float*)d_in[6];
    float* ys = (float*)d_out;

    const size_t XG_BYTES = (size_t)NSTEP * G4 * sizeof(float);   // 134 MB
    float* xg = (float*)d_ws;
    unsigned long long* slots =
        (unsigned long long*)((char*)d_ws + XG_BYTES);            // 16 KB

    // kill stale tags from previous graph replay (deterministic per call)
    hipMemsetAsync(slots, 0, 2 * HDIM * sizeof(unsigned long long), stream);

    dim3 gridA(G4 / 64, NSTEP / 64);
    gemm_xgates<<<gridA, 256, 0, stream>>>(xs, Wih, bih, bhh, xg);

    void* args[] = {(void*)&xg, (void*)&Whh, (void*)&h0, (void*)&c0,
                    (void*)&ys, (void*)&slots};
    hipLaunchCooperativeKernel((void*)lstm_rec, dim3(REC_G), dim3(REC_T),
                               args, 0, stream);
}

// Round 8
// 15549.390 us; speedup vs baseline: 1.3397x; 1.0003x over previous
//
#include <hip/hip_runtime.h>
#include <hip/hip_bf16.h>

// Problem constants: N=8192, Din=1024, H=1024, 4H=4096.
#define NSTEP 8192
#define DIN   1024
#define HDIM  1024
#define G4    4096

typedef float f32x4 __attribute__((ext_vector_type(4)));

// ---------------------------------------------------------------------------
// Phase A: x_gates[n][m] = dot(xs[n,:], W_ih[m,:]) + b_ih[m] + b_hh[m]
// ---------------------------------------------------------------------------
__global__ __launch_bounds__(256) void gemm_xgates(
    const float* __restrict__ xs,    // [8192,1024]
    const float* __restrict__ Wih,   // [4096,1024]
    const float* __restrict__ bih,   // [4096]
    const float* __restrict__ bhh,   // [4096]
    float* __restrict__ xg)          // [8192,4096]
{
    __shared__ float a_s[32][68];
    __shared__ float b_s[32][68];

    const int bm = blockIdx.x;
    const int bn = blockIdx.y;
    const int tid = threadIdx.x;
    const int tx = tid & 15;
    const int ty = tid >> 4;

    float acc[4][4] = {};

    for (int k0 = 0; k0 < DIN; k0 += 32) {
        #pragma unroll
        for (int s = tid; s < 512; s += 256) {
            const int r  = s >> 3;
            const int kk = (s & 7) << 2;
            const float4 av = *(const float4*)&xs[(size_t)(bn * 64 + r) * DIN + k0 + kk];
            a_s[kk + 0][r] = av.x; a_s[kk + 1][r] = av.y;
            a_s[kk + 2][r] = av.z; a_s[kk + 3][r] = av.w;
            const float4 bv = *(const float4*)&Wih[(size_t)(bm * 64 + r) * DIN + k0 + kk];
            b_s[kk + 0][r] = bv.x; b_s[kk + 1][r] = bv.y;
            b_s[kk + 2][r] = bv.z; b_s[kk + 3][r] = bv.w;
        }
        __syncthreads();

        #pragma unroll
        for (int k = 0; k < 32; ++k) {
            const float4 a = *(const float4*)&a_s[k][ty << 2];
            const float4 b = *(const float4*)&b_s[k][tx << 2];
            acc[0][0] = fmaf(a.x, b.x, acc[0][0]); acc[0][1] = fmaf(a.x, b.y, acc[0][1]);
            acc[0][2] = fmaf(a.x, b.z, acc[0][2]); acc[0][3] = fmaf(a.x, b.w, acc[0][3]);
            acc[1][0] = fmaf(a.y, b.x, acc[1][0]); acc[1][1] = fmaf(a.y, b.y, acc[1][1]);
            acc[1][2] = fmaf(a.y, b.z, acc[1][2]); acc[1][3] = fmaf(a.y, b.w, acc[1][3]);
            acc[2][0] = fmaf(a.z, b.x, acc[2][0]); acc[2][1] = fmaf(a.z, b.y, acc[2][1]);
            acc[2][2] = fmaf(a.z, b.z, acc[2][2]); acc[2][3] = fmaf(a.z, b.w, acc[2][3]);
            acc[3][0] = fmaf(a.w, b.x, acc[3][0]); acc[3][1] = fmaf(a.w, b.y, acc[3][1]);
            acc[3][2] = fmaf(a.w, b.z, acc[3][2]); acc[3][3] = fmaf(a.w, b.w, acc[3][3]);
        }
        __syncthreads();
    }

    const int m0 = bm * 64 + (tx << 2);
    const float4 bias = make_float4(bih[m0 + 0] + bhh[m0 + 0],
                                    bih[m0 + 1] + bhh[m0 + 1],
                                    bih[m0 + 2] + bhh[m0 + 2],
                                    bih[m0 + 3] + bhh[m0 + 3]);
    #pragma unroll
    for (int u = 0; u < 4; ++u) {
        const int n = bn * 64 + (ty << 2) + u;
        float4 v = make_float4(acc[u][0] + bias.x, acc[u][1] + bias.y,
                               acc[u][2] + bias.z, acc[u][3] + bias.w);
        *(float4*)&xg[(size_t)n * G4 + m0] = v;
    }
}

// ---------------------------------------------------------------------------
// Phase B: persistent recurrence. 128 WGs x 512 threads (cooperative).
// R7 structure (wave-autonomous rows, W pinned in VGPRs via waves_per_eu(2,2),
// data-as-flag slot exchange, one barrier/step) with ONE change:
// RAW BARRIER. __syncthreads emits s_waitcnt vmcnt(0) before s_barrier, which
// serially drains the publish store ack + ys store ack + 4 xg HBM prefetch
// loads (~900cyc) every step — putting the deliberately-off-path vmem ops
// back ON the critical path. LDS correctness needs only lgkmcnt(0) (ds_write
// of h_lds + ds_permute shfl). Publish visibility is carried by the
// data-as-flag tag; ys has no in-kernel reader; xg regs get compiler-
// inserted waits at their USE (hidden behind the poll). Memory-clobber asm
// on both sides of s_barrier blocks IR-level reordering of LDS ops across it.
// Slot overwrite safety unchanged from R5/R7 (poll load itself snapshots the
// value; tag-3 overwrite of a parity line requires every WG passed the tag-2
// poll, which requires every WG's tag-1 snapshot already in registers).
// ---------------------------------------------------------------------------
#define REC_G 128
#define REC_T 512
#define HPW   8

#define STEP_BARRIER() do {                                   \
    asm volatile("s_waitcnt lgkmcnt(0)" ::: "memory");        \
    __builtin_amdgcn_s_barrier();                             \
    asm volatile("" ::: "memory");                            \
} while (0)

__global__ __attribute__((amdgpu_waves_per_eu(2, 2)))
__launch_bounds__(REC_T) void lstm_rec(
    const float* __restrict__ xg,    // [NSTEP, 4096]
    const float* __restrict__ Whh,   // [4096, 1024]
    const float* __restrict__ h0,    // [1024]
    const float* __restrict__ c0,    // [1024]
    float* __restrict__ ys,          // [NSTEP, 1024]
    unsigned long long* slots)       // [2][1024] ws, memset 0 pre-launch
{
    __shared__ float h_lds[2][HDIM];

    const int tid   = threadIdx.x;
    const int lane  = tid & 63;
    const int wv    = tid >> 6;           // 0..7
    const int wg    = blockIdx.x;         // 0..127
    const int jglob = wg * HPW + wv;      // this wave's hidden index

    // ---- stage W: w[r*4+i] = Whh[r*HDIM + jglob][4*(lane+64i) .. +3] ----
    f32x4 w[16];
    #pragma unroll
    for (int r = 0; r < 4; ++r) {
        const float* wb = Whh + (size_t)(r * HDIM + jglob) * HDIM;
        #pragma unroll
        for (int i = 0; i < 4; ++i)
            w[r * 4 + i] = *(const f32x4*)(wb + ((lane + (i << 6)) << 2));
    }
    asm volatile("" : "+v"(w[0]), "+v"(w[1]), "+v"(w[2]), "+v"(w[3]),
                      "+v"(w[4]), "+v"(w[5]), "+v"(w[6]), "+v"(w[7]));
    asm volatile("" : "+v"(w[8]), "+v"(w[9]), "+v"(w[10]), "+v"(w[11]),
                      "+v"(w[12]), "+v"(w[13]), "+v"(w[14]), "+v"(w[15]));

    // ---- init: h0 -> buffer 0; c + xg rows 0,1 redundant on all lanes ----
    ((float2*)h_lds[0])[tid] = ((const float2*)h0)[tid];
    float c_reg = c0[jglob];                       // wave-broadcast load
    float xc0 = xg[0 * HDIM + jglob];
    float xc1 = xg[1 * HDIM + jglob];
    float xc2 = xg[2 * HDIM + jglob];
    float xc3 = xg[3 * HDIM + jglob];
    float xn0 = xg[(size_t)G4 + 0 * HDIM + jglob];
    float xn1 = xg[(size_t)G4 + 1 * HDIM + jglob];
    float xn2 = xg[(size_t)G4 + 2 * HDIM + jglob];
    float xn3 = xg[(size_t)G4 + 3 * HDIM + jglob];
    __syncthreads();

    for (int t = 0; t < NSTEP; ++t) {
        const f32x4* hb = (const f32x4*)h_lds[t & 1];

        // ---- dot: W in VGPRs, h from LDS (4 ds_read_b128, consecutive) ----
        float a0 = 0.f, a1 = 0.f, a2 = 0.f, a3 = 0.f;
        #pragma unroll
        for (int i = 0; i < 4; ++i) {
            const f32x4 hv = hb[lane + (i << 6)];
            a0 = fmaf(w[0  + i].x, hv.x, a0); a0 = fmaf(w[0  + i].y, hv.y, a0);
            a0 = fmaf(w[0  + i].z, hv.z, a0); a0 = fmaf(w[0  + i].w, hv.w, a0);
            a1 = fmaf(w[4  + i].x, hv.x, a1); a1 = fmaf(w[4  + i].y, hv.y, a1);
            a1 = fmaf(w[4  + i].z, hv.z, a1); a1 = fmaf(w[4  + i].w, hv.w, a1);
            a2 = fmaf(w[8  + i].x, hv.x, a2); a2 = fmaf(w[8  + i].y, hv.y, a2);
            a2 = fmaf(w[8  + i].z, hv.z, a2); a2 = fmaf(w[8  + i].w, hv.w, a2);
            a3 = fmaf(w[12 + i].x, hv.x, a3); a3 = fmaf(w[12 + i].y, hv.y, a3);
            a3 = fmaf(w[12 + i].z, hv.z, a3); a3 = fmaf(w[12 + i].w, hv.w, a3);
        }
        #pragma unroll
        for (int m = 1; m < 64; m <<= 1) {
            a0 += __shfl_xor(a0, m);
            a1 += __shfl_xor(a1, m);
            a2 += __shfl_xor(a2, m);
            a3 += __shfl_xor(a3, m);
        }

        // ---- gating: redundant on all 64 lanes (same cycles as 1 lane) ----
        const float gi = a0 + xc0;
        const float gf = a1 + xc1;
        const float gg = a2 + xc2;
        const float go = a3 + xc3;
        const float i_ = 1.f / (1.f + __expf(-gi));
        const float f_ = 1.f / (1.f + __expf(-gf));
        const float g_ = 2.f / (1.f + __expf(-2.f * gg)) - 1.f;
        const float o_ = 1.f / (1.f + __expf(-go));
        c_reg = f_ * c_reg + i_ * g_;
        const float h_ = o_ * (2.f / (1.f + __expf(-2.f * c_reg)) - 1.f);

        // ---- publish ASAP (lane 0), then off-critical-path work ----
        if (lane == 0) {
            if (t + 1 < NSTEP) {
                const unsigned long long pk =
                    ((unsigned long long)(unsigned)(t + 1) << 32) |
                    (unsigned long long)__float_as_uint(h_);
                __hip_atomic_store(&slots[((t + 1) & 1) * HDIM + jglob], pk,
                                   __ATOMIC_RELAXED, __HIP_MEMORY_SCOPE_AGENT);
            }
            ys[(size_t)t * HDIM + jglob] = h_;
        }
        xc0 = xn0; xc1 = xn1; xc2 = xn2; xc3 = xn3;
        if (t + 2 < NSTEP) {
            const size_t xb = (size_t)(t + 2) * G4 + jglob;
            xn0 = xg[xb + 0 * HDIM];
            xn1 = xg[xb + 1 * HDIM];
            xn2 = xg[xb + 2 * HDIM];
            xn3 = xg[xb + 3 * HDIM];
        }
        if (t + 1 == NSTEP) break;

        // ---- poll own 2 slots (both loads in flight per iteration) ----
        {
            const unsigned long long* sp = slots + ((t + 1) & 1) * HDIM;
            const unsigned long long want =
                (unsigned long long)(unsigned)(t + 1) << 32;
            unsigned long long s0, s1;
            do {
                s0 = __hip_atomic_load(&sp[2 * tid], __ATOMIC_RELAXED,
                                       __HIP_MEMORY_SCOPE_AGENT);
                s1 = __hip_atomic_load(&sp[2 * tid + 1], __ATOMIC_RELAXED,
                                       __HIP_MEMORY_SCOPE_AGENT);
            } while (s0 < want || s1 < want);
            float2 hv;
            hv.x = __uint_as_float((unsigned)s0);
            hv.y = __uint_as_float((unsigned)s1);
            ((float2*)h_lds[(t + 1) & 1])[tid] = hv;
        }
        // ---- raw barrier: lgkmcnt only, NO vmcnt drain ----
        STEP_BARRIER();
    }
}

// ---------------------------------------------------------------------------
extern "C" void kernel_launch(void* const* d_in, const int* in_sizes, int n_in,
                              void* d_out, int out_size, void* d_ws, size_t ws_size,
                              hipStream_t stream) {
    const float* xs  = (const float*)d_in[0];
    const float* Wih = (const float*)d_in[1];
    const float* Whh = (const float*)d_in[2];
    const float* bih = (const float*)d_in[3];
    const float* bhh = (const float*)d_in[4];
    const float* h0  = (const float*)d_in[5];
    const float* c0  = (const float*)d_in[6];
    float* ys = (float*)d_out;

    const size_t XG_BYTES = (size_t)NSTEP * G4 * sizeof(float);   // 134 MB
    float* xg = (float*)d_ws;
    unsigned long long* slots =
        (unsigned long long*)((char*)d_ws + XG_BYTES);            // 16 KB

    // kill stale tags from previous graph replay (deterministic per call)
    hipMemsetAsync(slots, 0, 2 * HDIM * sizeof(unsigned long long), stream);

    dim3 gridA(G4 / 64, NSTEP / 64);
    gemm_xgates<<<gridA, 256, 0, stream>>>(xs, Wih, bih, bhh, xg);

    void* args[] = {(void*)&xg, (void*)&Whh, (void*)&h0, (void*)&c0,
                    (void*)&ys, (void*)&slots};
    hipLaunchCooperativeKernel((void*)lstm_rec, dim3(REC_G), dim3(REC_T),
                               args, 0, stream);
}